// Round 18
// baseline (1886.319 us; speedup 1.0000x reference)
//
#include <hip/hip_runtime.h>
#include <hip/hip_bf16.h>

#define T_ 1024
#define B_ 64
#define H_ 128
#define G_ 512   // 4*H
#define E_ 128
#define V_ 32
#define N_ 8

// ---- cross-lane helpers (compile-time controls) ---------------------------
template<int CTRL>
__device__ __forceinline__ float dppf(float x) {
    return __int_as_float(__builtin_amdgcn_update_dpp(0, __float_as_int(x), CTRL, 0xF, 0xF, true));
}
template<int CTRL>
__device__ __forceinline__ int dppi(int x) {
    return __builtin_amdgcn_update_dpp(0, x, CTRL, 0xF, 0xF, true);
}
template<int OFF>
__device__ __forceinline__ float swzf(float x) {
    return __int_as_float(__builtin_amdgcn_ds_swizzle(__float_as_int(x), OFF));
}
// DPP ctrl constants: quad_perm[a,b,c,d] = a|b<<2|c<<4|d<<6
#define QP_XOR1 0xB1   // [1,0,3,2]  == exact lane^1 exchange
#define QP_XOR2 0x4E   // [2,3,0,1]  == exact lane^2 exchange
#define QP_BC0  0x00
#define QP_BC1  0x55
#define QP_BC2  0xAA
#define QP_BC3  0xFF
#define ROW_ROR8 0x128 // row_ror:8 == exact lane^8 exchange within 16-row
// ds_swizzle BitMode: (xor<<10)|(or<<5)|and
#define SWZ_XOR4  0x101F
#define SWZ_XOR16 0x401F

// ---------------------------------------------------------------------------
// K0: proj[dir][v][g] = b_dir[g] + sum_e W_ih_dir[g][e] * emb[v][e]
// (verbatim — passing)
// ---------------------------------------------------------------------------
__global__ __launch_bounds__(512) void proj_kernel(
    const float* __restrict__ emb,
    const float* __restrict__ Wih_f, const float* __restrict__ b_f,
    const float* __restrict__ Wih_b, const float* __restrict__ b_b,
    float* __restrict__ proj)
{
    int wg  = blockIdx.x;
    int dir = wg >> 5;
    int v   = wg & 31;
    const float* W    = dir ? Wih_b : Wih_f;
    const float* bias = dir ? b_b   : b_f;
    int tid = threadIdx.x;

    __shared__ float4 e_l[E_ / 4];
    if (tid < E_ / 4) e_l[tid] = ((const float4*)(emb + (size_t)v * E_))[tid];
    __syncthreads();

    float acc = bias[tid];
    const float4* wr = (const float4*)(W + (size_t)tid * E_);
#pragma unroll
    for (int k = 0; k < 32; ++k) {
        float4 wv = wr[k], ev = e_l[k];
        acc += wv.x * ev.x;
        acc += wv.y * ev.y;
        acc += wv.z * ev.z;
        acc += wv.w * ev.w;
    }
    proj[((size_t)dir * V_ + v) * G_ + tid] = acc;
}

// ---------------------------------------------------------------------------
// K0b: prestage W into thread-linear, pre-rotated layout:
// wpre[dir*16K + m*1K + tid] = r12's (m<8 ? w0[k=m&7] : w1[k=m&7]) for thread
// tid of block (dir, b) — i.e. W_hh[(g)*128+j][c*32 + ((k+2c)&7)*4 ..] with
// j=tid>>3, q=tid&7, p=q&1, c=q>>1, g = (m<8 ? 2p : 2p+1).
// Coalesced consumption: per load instr, lanes read consecutive float4s.
// ---------------------------------------------------------------------------
__global__ __launch_bounds__(512) void prestage_kernel(
    const float* __restrict__ Whh_f, const float* __restrict__ Whh_b,
    float4* __restrict__ wpre)
{
    int idx  = blockIdx.x * 512 + threadIdx.x;   // 0..32767
    int dir  = idx >> 14;
    int m    = (idx >> 10) & 15;
    int tid2 = idx & 1023;
    int j = tid2 >> 3, q = tid2 & 7, p = q & 1, c = q >> 1;
    int g = (m < 8) ? (2 * p) : (2 * p + 1);
    int k = m & 7;
    const float* W = dir ? Whh_b : Whh_f;
    const float4* src = (const float4*)(W + (size_t)(g * H_ + j) * H_ + c * 32);
    wpre[idx] = src[(k + 2 * c) & 7];
}

// ---------------------------------------------------------------------------
// K1: LSTM — r12 structure/math VERBATIM; W feed split LDS ∥ L2.
// r12-r17 model: r12 is L2-feed-bound (256KB/block/step ≈ 33 TB/s aggregate
// = the L2 ceiling; r16 proved per-CU port, r17 proved not-DS). Fix: feed W
// through BOTH pipes — k=0..3 of each gate row from LDS (128KB, staged once,
// bank-perfect Wl[m][tid]), k=4..7 streamed from wpre (coalesced; pointer-
// opacity asm prevents hoist->spill). FMA order per k identical to r12 ->
// bit-identical sums. Single barrier, reduce/act/gather/FC verbatim.
// ---------------------------------------------------------------------------
__global__ __launch_bounds__(1024)
__attribute__((amdgpu_waves_per_eu(4, 4)))
void lstm_kernel(
    const int*   __restrict__ x,
    const float* __restrict__ proj,   // [2][V][G]
    const float* __restrict__ fcW,    // [8][256]
    const float4* __restrict__ wpre,  // [2][16][1024]
    float* __restrict__ part)         // [2][T][B][8]
{
    int wg  = blockIdx.x;
    int dir = wg >> 6;
    int b   = wg & 63;
    int tid = threadIdx.x;
    int j   = tid >> 3;        // 0..127
    int q   = tid & 7;
    int c   = q >> 1;          // h-chunk 0..3
    int which = c & 1;
    int gate_own = 2 * (q & 1) + which;   // quad {0,1,2,3} -> gates {0,2,1,3}

    __shared__ float4 Wl[8][1024];       // 128KB: [k][tid]=w0[k], [4+k][tid]=w1[k], k=0..3
    __shared__ int    tok_l[T_];         // 4KB
    __shared__ float4 hb4[2][H_ / 4];    // 1KB double-buffered h

    tok_l[tid] = x[(size_t)b * T_ + tid];
    if (tid < H_) ((float*)hb4[0])[tid] = 0.f;

    int nw = tid >> 6;      // FC logit (waves 0-7)
    int e  = tid & 63;      // FC element pair
    float fw0 = 0.f, fw1 = 0.f;
    if (tid < 512) {
        fw0 = fcW[nw * 256 + dir * H_ + 2 * e];
        fw1 = fcW[nw * 256 + dir * H_ + 2 * e + 1];
    }

    // stage LDS half of W (k=0..3 of both gate rows), coalesced from wpre
    const float4* wpre_d = wpre + (size_t)dir * 16 * 1024;
#pragma unroll
    for (int m = 0; m < 4; ++m) Wl[m][tid]     = wpre_d[m * 1024 + tid];        // w0 k=m
#pragma unroll
    for (int m = 0; m < 4; ++m) Wl[4 + m][tid] = wpre_d[(8 + m) * 1024 + tid];  // w1 k=m

    // streamed half pointers (k=4..7): w0 at m=4..7, w1 at m=12..15
    const float4* wsA = wpre_d + 4 * 1024 + tid;
    const float4* wsB = wpre_d + 12 * 1024 + tid;

    asm volatile("" : "+v"(fw0), "+v"(fw1));

    const float* projd = proj + (size_t)dir * (V_ * G_);
    int gown = gate_own * H_ + j;
    float cc = 0.f;
    __syncthreads();

    float pv_c = projd[tok_l[dir ? (T_ - 1) : 0] * G_ + gown];

    int cur = 0;
    for (int t = 0; t < T_; ++t) {
        int tt = dir ? (T_ - 1 - t) : t;
        int tn = (t + 1 < T_) ? (t + 1) : t;
        float pv_n = projd[tok_l[dir ? (T_ - 1 - tn) : tn] * G_ + gown];

        // pointer opacity: loads below cannot be hoisted out of the loop
        // (hoist -> live-across-loop -> allocator spills = the r3-r7 trap)
        asm volatile("" : "+v"(wsA), "+v"(wsB));
        float4 s4 = wsA[0 * 1024], s5 = wsA[1 * 1024];
        float4 s6 = wsA[2 * 1024], s7 = wsA[3 * 1024];
        float4 u4 = wsB[0 * 1024], u5 = wsB[1 * 1024];
        float4 u6 = wsB[2 * 1024], u7 = wsB[3 * 1024];

        const float4* hb = (const float4*)hb4[cur];
        float a0 = 0.f, a1 = 0.f;
        // k=0..3 from LDS (same per-k term order as r12)
#pragma unroll
        for (int k = 0; k < 4; ++k) {
            float4 hv = hb[c * 8 + ((k + 2 * c) & 7)];
            float4 w0v = Wl[k][tid], w1v = Wl[4 + k][tid];
            a0 += w0v.x * hv.x; a0 += w0v.y * hv.y; a0 += w0v.z * hv.z; a0 += w0v.w * hv.w;
            a1 += w1v.x * hv.x; a1 += w1v.y * hv.y; a1 += w1v.z * hv.z; a1 += w1v.w * hv.w;
        }
        // k=4..7 from the L2 stream
        {
            float4 hv;
            hv = hb[c * 8 + ((4 + 2 * c) & 7)];
            a0 += s4.x * hv.x; a0 += s4.y * hv.y; a0 += s4.z * hv.z; a0 += s4.w * hv.w;
            a1 += u4.x * hv.x; a1 += u4.y * hv.y; a1 += u4.z * hv.z; a1 += u4.w * hv.w;
            hv = hb[c * 8 + ((5 + 2 * c) & 7)];
            a0 += s5.x * hv.x; a0 += s5.y * hv.y; a0 += s5.z * hv.z; a0 += s5.w * hv.w;
            a1 += u5.x * hv.x; a1 += u5.y * hv.y; a1 += u5.z * hv.z; a1 += u5.w * hv.w;
            hv = hb[c * 8 + ((6 + 2 * c) & 7)];
            a0 += s6.x * hv.x; a0 += s6.y * hv.y; a0 += s6.z * hv.z; a0 += s6.w * hv.w;
            a1 += u6.x * hv.x; a1 += u6.y * hv.y; a1 += u6.z * hv.z; a1 += u6.w * hv.w;
            hv = hb[c * 8 + ((7 + 2 * c) & 7)];
            a0 += s7.x * hv.x; a0 += s7.y * hv.y; a0 += s7.z * hv.z; a0 += s7.w * hv.w;
            a1 += u7.x * hv.x; a1 += u7.y * hv.y; a1 += u7.z * hv.z; a1 += u7.w * hv.w;
        }
        // reduce: XOR2 (DPP) then XOR4 (swizzle) — r12 tree, bit-identical
        a0 += dppf<QP_XOR2>(a0);
        a1 += dppf<QP_XOR2>(a1);
        a0 += swzf<SWZ_XOR4>(a0);
        a1 += swzf<SWZ_XOR4>(a1);

        float tot = which ? a1 : a0;
        tot += pv_c;
        float act = (gate_own == 2) ? tanhf(tot) : 1.f / (1.f + expf(-tot));

        // quad positions {0,1,2,3} hold gates {i,g,f,o} -> broadcast-gather
        float gi = dppf<QP_BC0>(act);
        float gg = dppf<QP_BC1>(act);
        float gf = dppf<QP_BC2>(act);
        float go = dppf<QP_BC3>(act);

        cc = gf * cc + gi * gg;
        float h = go * tanhf(cc);
        if (q == 0) ((float*)hb4[cur ^ 1])[j] = h;
        __syncthreads();                   // single barrier per step

        // FC on waves 0-7: wave nw computes logit nw (2 FMA + butterfly)
        if (tid < 512) {
            float2 h2 = ((const float2*)hb4[cur ^ 1])[e];
            float pa = fw0 * h2.x + fw1 * h2.y;
            pa += dppf<QP_XOR1>(pa);
            pa += dppf<QP_XOR2>(pa);
            pa += swzf<SWZ_XOR4>(pa);
            pa += dppf<ROW_ROR8>(pa);
            pa += swzf<SWZ_XOR16>(pa);
            float psum = pa + __int_as_float(__builtin_amdgcn_readlane(__float_as_int(pa), 32));
            if (e == 0) part[(((size_t)dir * T_ + tt) * B_ + b) * N_ + nw] = psum;
        }
        pv_c = pv_n;
        cur ^= 1;
    }
}

// ---------------------------------------------------------------------------
// K2: Viterbi — round-15 replicated-score all-DPP version VERBATIM (passing).
// ---------------------------------------------------------------------------
__global__ __launch_bounds__(64) void viterbi_kernel(
    const float* __restrict__ part,   // [2][T][B][8]
    const float* __restrict__ fc_b,
    const float* __restrict__ start_t,
    const float* __restrict__ end_t,
    const float* __restrict__ trans,  // [8][8]
    int* __restrict__ out)            // [B][T]
{
    int b = blockIdx.x;
    int l = threadIdx.x;
    int j = (l & 3) | ((l >> 1) & 4);
    bool b0c = (l & 1) != 0;
    bool b1c = (l & 2) != 0;
    bool b3c = (l & 8) != 0;
    int sh3 = 3 * j;

    __shared__ unsigned int hist_l[T_];

    float tr[8];
#pragma unroll
    for (int i = 0; i < 8; ++i) tr[i] = trans[i * 8 + j];   // column j
    float endt_r[8];
#pragma unroll
    for (int i = 0; i < 8; ++i) endt_r[i] = end_t[i];
    float fcb = fc_b[j];
    const float* pf = part;
    const float* pb = part + (size_t)T_ * B_ * N_;

    float s[8];

#define SHARE(xx) { \
    float y_ = dppf<QP_XOR1>(xx); \
    float A0 = b0c ? y_ : (xx); float A1 = b0c ? (xx) : y_; \
    float A0x = dppf<QP_XOR2>(A0); float A1x = dppf<QP_XOR2>(A1); \
    float B00 = b1c ? A0x : A0; float B10 = b1c ? A0 : A0x; \
    float B01 = b1c ? A1x : A1; float B11 = b1c ? A1 : A1x; \
    float C00 = dppf<ROW_ROR8>(B00); float C01 = dppf<ROW_ROR8>(B01); \
    float C10 = dppf<ROW_ROR8>(B10); float C11 = dppf<ROW_ROR8>(B11); \
    s[0] = b3c ? C00 : B00;  s[1] = b3c ? C01 : B01; \
    s[2] = b3c ? C10 : B10;  s[3] = b3c ? C11 : B11; \
    s[4] = b3c ? B00 : C00;  s[5] = b3c ? B01 : C01; \
    s[6] = b3c ? B10 : C10;  s[7] = b3c ? B11 : C11; }

#define VSTEP(emv, tcur) { \
    float v0 = (s[0] + tr[0]) + (emv); \
    float v1 = (s[1] + tr[1]) + (emv); \
    float v2 = (s[2] + tr[2]) + (emv); \
    float v3 = (s[3] + tr[3]) + (emv); \
    float v4 = (s[4] + tr[4]) + (emv); \
    float v5 = (s[5] + tr[5]) + (emv); \
    float v6 = (s[6] + tr[6]) + (emv); \
    float v7 = (s[7] + tr[7]) + (emv); \
    float va = (v1 > v0) ? v1 : v0;  int ia = (v1 > v0) ? 1 : 0; \
    float vb = (v3 > v2) ? v3 : v2;  int ib = (v3 > v2) ? 3 : 2; \
    float vc = (v5 > v4) ? v5 : v4;  int ic = (v5 > v4) ? 5 : 4; \
    float vd = (v7 > v6) ? v7 : v6;  int id_ = (v7 > v6) ? 7 : 6; \
    float ve = (vb > va) ? vb : va;  int ie = (vb > va) ? ib : ia; \
    float vf = (vd > vc) ? vd : vc;  int if_ = (vd > vc) ? id_ : ic; \
    float vg = (vf > ve) ? vf : ve;  int ig = (vf > ve) ? if_ : ie; \
    SHARE(vg) \
    unsigned pk = (unsigned)ig << sh3; \
    pk |= (unsigned)dppi<QP_XOR1>((int)pk); \
    pk |= (unsigned)dppi<QP_XOR2>((int)pk); \
    pk |= (unsigned)dppi<ROW_ROR8>((int)pk); \
    if (l == 0) hist_l[tcur] = pk; }

#define LOADSUB(dst, ss) { \
    int t0_ = (ss) * 8; \
    _Pragma("unroll") \
    for (int p = 0; p < 8; ++p) { \
        size_t base = ((size_t)(t0_ + p) * B_ + b) * N_ + j; \
        dst[p] = (pf[base] + pb[base]) + fcb; } }

#define PROC8(arr, t0_) { \
    VSTEP(arr[0], (t0_) + 0) VSTEP(arr[1], (t0_) + 1) \
    VSTEP(arr[2], (t0_) + 2) VSTEP(arr[3], (t0_) + 3) \
    VSTEP(arr[4], (t0_) + 4) VSTEP(arr[5], (t0_) + 5) \
    VSTEP(arr[6], (t0_) + 6) VSTEP(arr[7], (t0_) + 7) }

    float emA[8], emB[8];
    LOADSUB(emA, 0)
    LOADSUB(emB, 1)

    {
        float x0 = start_t[j] + emA[0];
        SHARE(x0)
    }
    VSTEP(emA[1], 1) VSTEP(emA[2], 2) VSTEP(emA[3], 3) VSTEP(emA[4], 4)
    VSTEP(emA[5], 5) VSTEP(emA[6], 6) VSTEP(emA[7], 7)

    for (int ss = 1; ss < 127; ss += 2) {
        LOADSUB(emA, ss + 1)
        PROC8(emB, ss * 8)
        LOADSUB(emB, ss + 2)
        PROC8(emA, (ss + 1) * 8)
    }
    PROC8(emB, 127 * 8)

    int tag;
    {
        float v0 = s[0] + endt_r[0];
        float v1 = s[1] + endt_r[1];
        float v2 = s[2] + endt_r[2];
        float v3 = s[3] + endt_r[3];
        float v4 = s[4] + endt_r[4];
        float v5 = s[5] + endt_r[5];
        float v6 = s[6] + endt_r[6];
        float v7 = s[7] + endt_r[7];
        float va = (v1 > v0) ? v1 : v0;  int ia = (v1 > v0) ? 1 : 0;
        float vb = (v3 > v2) ? v3 : v2;  int ib = (v3 > v2) ? 3 : 2;
        float vc = (v5 > v4) ? v5 : v4;  int ic = (v5 > v4) ? 5 : 4;
        float vd = (v7 > v6) ? v7 : v6;  int id_ = (v7 > v6) ? 7 : 6;
        float ve = (vb > va) ? vb : va;  int ie = (vb > va) ? ib : ia;
        float vf = (vd > vc) ? vd : vc;  int if_ = (vd > vc) ? id_ : ic;
        tag = (vf > ve) ? if_ : ie;
    }
    if (l == 0) out[(size_t)b * T_ + (T_ - 1)] = tag;
    __syncthreads();

    for (int t0b = T_ - 16; t0b >= 0; t0b -= 16) {
        unsigned int pk[16];
#pragma unroll
        for (int qq = 0; qq < 16; ++qq) pk[qq] = hist_l[t0b + qq];
#pragma unroll
        for (int qq = 15; qq >= 0; --qq) {
            int t = t0b + qq;
            if (t >= 1) {
                tag = (pk[qq] >> (3 * tag)) & 7;
                if (l == 0) out[(size_t)b * T_ + t - 1] = tag;
            }
        }
    }
#undef SHARE
#undef VSTEP
#undef LOADSUB
#undef PROC8
}

extern "C" void kernel_launch(void* const* d_in, const int* in_sizes, int n_in,
                              void* d_out, int out_size, void* d_ws, size_t ws_size,
                              hipStream_t stream) {
    (void)in_sizes; (void)n_in; (void)out_size; (void)ws_size;
    const int*   x      = (const int*)  d_in[0];
    const float* emb    = (const float*)d_in[1];
    const float* Wih_f  = (const float*)d_in[2];
    const float* Whh_f  = (const float*)d_in[3];
    const float* b_f    = (const float*)d_in[4];
    const float* Wih_b  = (const float*)d_in[5];
    const float* Whh_b  = (const float*)d_in[6];
    const float* b_b    = (const float*)d_in[7];
    const float* fcW    = (const float*)d_in[8];
    const float* fcb    = (const float*)d_in[9];
    const float* startt = (const float*)d_in[10];
    const float* endt   = (const float*)d_in[11];
    const float* trans  = (const float*)d_in[12];

    float*  proj = (float*)d_ws;                   // 32768 floats = 128 KB
    float*  part = proj + 2 * V_ * G_;             // 1048576 floats = 4 MB
    float4* wpre = (float4*)(part + 2 * T_ * B_ * N_);  // 32768 float4 = 512 KB
    int*    out  = (int*)d_out;

    proj_kernel<<<64, 512, 0, stream>>>(emb, Wih_f, b_f, Wih_b, b_b, proj);
    prestage_kernel<<<64, 512, 0, stream>>>(Whh_f, Whh_b, wpre);
    lstm_kernel<<<128, 1024, 0, stream>>>(x, proj, fcW, wpre, part);
    viterbi_kernel<<<64, 64, 0, stream>>>(part, fcb, startt, endt, trans, out);
}

// Round 19
// 1139.728 us; speedup vs baseline: 1.6551x; 1.6551x over previous
//
#include <hip/hip_runtime.h>
#include <hip/hip_bf16.h>

#define T_ 1024
#define B_ 64
#define H_ 128
#define G_ 512   // 4*H
#define E_ 128
#define V_ 32
#define N_ 8

// ---- cross-lane helpers (compile-time controls) ---------------------------
template<int CTRL>
__device__ __forceinline__ float dppf(float x) {
    return __int_as_float(__builtin_amdgcn_update_dpp(0, __float_as_int(x), CTRL, 0xF, 0xF, true));
}
template<int CTRL>
__device__ __forceinline__ int dppi(int x) {
    return __builtin_amdgcn_update_dpp(0, x, CTRL, 0xF, 0xF, true);
}
template<int OFF>
__device__ __forceinline__ float swzf(float x) {
    return __int_as_float(__builtin_amdgcn_ds_swizzle(__float_as_int(x), OFF));
}
// DPP ctrl constants: quad_perm[a,b,c,d] = a|b<<2|c<<4|d<<6
#define QP_XOR1 0xB1   // [1,0,3,2]  == exact lane^1 exchange
#define QP_XOR2 0x4E   // [2,3,0,1]  == exact lane^2 exchange
#define QP_BC0  0x00
#define QP_BC1  0x55
#define QP_BC2  0xAA
#define QP_BC3  0xFF
#define ROW_ROR8 0x128 // row_ror:8 == exact lane^8 exchange within 16-row
// ds_swizzle BitMode: (xor<<10)|(or<<5)|and
#define SWZ_XOR4  0x101F
#define SWZ_XOR16 0x401F

// ---------------------------------------------------------------------------
// K0: proj[dir][v][g] = b_dir[g] + sum_e W_ih_dir[g][e] * emb[v][e]
// (verbatim — passing)
// ---------------------------------------------------------------------------
__global__ __launch_bounds__(512) void proj_kernel(
    const float* __restrict__ emb,
    const float* __restrict__ Wih_f, const float* __restrict__ b_f,
    const float* __restrict__ Wih_b, const float* __restrict__ b_b,
    float* __restrict__ proj)
{
    int wg  = blockIdx.x;
    int dir = wg >> 5;
    int v   = wg & 31;
    const float* W    = dir ? Wih_b : Wih_f;
    const float* bias = dir ? b_b   : b_f;
    int tid = threadIdx.x;

    __shared__ float4 e_l[E_ / 4];
    if (tid < E_ / 4) e_l[tid] = ((const float4*)(emb + (size_t)v * E_))[tid];
    __syncthreads();

    float acc = bias[tid];
    const float4* wr = (const float4*)(W + (size_t)tid * E_);
#pragma unroll
    for (int k = 0; k < 32; ++k) {
        float4 wv = wr[k], ev = e_l[k];
        acc += wv.x * ev.x;
        acc += wv.y * ev.y;
        acc += wv.z * ev.z;
        acc += wv.w * ev.w;
    }
    proj[((size_t)dir * V_ + v) * G_ + tid] = acc;
}

// ---------------------------------------------------------------------------
// K1: LSTM — r12 kernel VERBATIM (best of 18 rounds: 1007us).
// Multi-pipe-saturated local optimum: max(per-CU L2 W-stream ~2000-2600cyc,
// DS h-reads ~1536cyc, VALU ~1230cyc)/step with near-full overlap. Seven
// structural redesigns (AGPR residency r8/11/13/14, dual-chain r16, 16-seg
// r17, LDS∥L2 feed-split r18) all regressed by overloading one pipe.
// ---------------------------------------------------------------------------
__global__ __launch_bounds__(1024)
__attribute__((amdgpu_waves_per_eu(4, 4)))
void lstm_kernel(
    const int*   __restrict__ x,
    const float* __restrict__ Whh_f, const float* __restrict__ Whh_b,
    const float* __restrict__ proj,   // [2][V][G]
    const float* __restrict__ fcW,    // [8][256]
    float* __restrict__ part)         // [2][T][B][8]
{
    int wg  = blockIdx.x;
    int dir = wg >> 6;
    int b   = wg & 63;
    int tid = threadIdx.x;
    int j   = tid >> 3;        // 0..127
    int q   = tid & 7;
    int p   = q & 1;           // gate pair -> rows {2p, 2p+1}
    int c   = q >> 1;          // h-chunk 0..3
    int which = c & 1;         // own gate within pair
    int gate_own = 2 * p + which;   // quad positions {0,1,2,3} -> gates {0,2,1,3}

    __shared__ union { int tok[T_]; char pad[83 * 1024]; } tu;  // 1-block/CU forcer
    __shared__ float4 hb4[2][H_ / 4];   // double-buffered h

    tu.tok[tid] = x[(size_t)b * T_ + tid];
    if (tid < H_) ((float*)hb4[0])[tid] = 0.f;

    int nw = tid >> 6;      // FC logit (waves 0-7)
    int e  = tid & 63;      // FC element pair
    float fw0 = 0.f, fw1 = 0.f;
    if (tid < 512) {
        fw0 = fcW[nw * 256 + dir * H_ + 2 * e];
        fw1 = fcW[nw * 256 + dir * H_ + 2 * e + 1];
    }

    const float* Whh = dir ? Whh_b : Whh_f;

    // w0/w1[k] = W_hh[(row)*128+j][ c*32 + ((k+2c)&7)*4 .. +4 )
    float4 w0[8], w1[8];
    {
        const float4* wr0 = (const float4*)(Whh + (size_t)((2 * p) * H_ + j) * H_ + c * 32);
        const float4* wr1 = (const float4*)(Whh + (size_t)((2 * p + 1) * H_ + j) * H_ + c * 32);
#pragma unroll
        for (int k = 0; k < 8; ++k) {
            w0[k] = wr0[(k + 2 * c) & 7];
            w1[k] = wr1[(k + 2 * c) & 7];
        }
    }
#pragma unroll
    for (int k = 0; k < 8; ++k) {
        asm volatile("" : "+v"(w0[k].x), "+v"(w0[k].y), "+v"(w0[k].z), "+v"(w0[k].w));
        asm volatile("" : "+v"(w1[k].x), "+v"(w1[k].y), "+v"(w1[k].z), "+v"(w1[k].w));
    }
    asm volatile("" : "+v"(fw0), "+v"(fw1));

    const float* projd = proj + (size_t)dir * (V_ * G_);
    int gown = gate_own * H_ + j;
    float cc = 0.f;
    __syncthreads();

    float pv_c = projd[tu.tok[dir ? (T_ - 1) : 0] * G_ + gown];

    int cur = 0;
    for (int t = 0; t < T_; ++t) {
        int tt = dir ? (T_ - 1 - t) : t;
        int tn = (t + 1 < T_) ? (t + 1) : t;
        float pv_n = projd[tu.tok[dir ? (T_ - 1 - tn) : tn] * G_ + gown];

        const float4* hb = (const float4*)hb4[cur];
        float a0 = 0.f, a1 = 0.f;
#pragma unroll
        for (int k = 0; k < 8; ++k) {
            float4 hv = hb[c * 8 + ((k + 2 * c) & 7)];
            float4 u0 = w0[k], u1 = w1[k];
            a0 += u0.x * hv.x; a0 += u0.y * hv.y; a0 += u0.z * hv.z; a0 += u0.w * hv.w;
            a1 += u1.x * hv.x; a1 += u1.y * hv.y; a1 += u1.z * hv.z; a1 += u1.w * hv.w;
        }
        // combine the 4 chunks: XOR2 (DPP) then XOR4 (swizzle)
        a0 += dppf<QP_XOR2>(a0);
        a1 += dppf<QP_XOR2>(a1);
        a0 += swzf<SWZ_XOR4>(a0);
        a1 += swzf<SWZ_XOR4>(a1);

        float tot = which ? a1 : a0;
        tot += pv_c;
        float act = (gate_own == 2) ? tanhf(tot) : 1.f / (1.f + expf(-tot));

        // quad positions {0,1,2,3} hold gates {i,g,f,o} -> broadcast-gather
        float gi = dppf<QP_BC0>(act);
        float gg = dppf<QP_BC1>(act);
        float gf = dppf<QP_BC2>(act);
        float go = dppf<QP_BC3>(act);

        cc = gf * cc + gi * gg;
        float h = go * tanhf(cc);
        if (q == 0) ((float*)hb4[cur ^ 1])[j] = h;
        __syncthreads();                   // single barrier per step

        // FC on waves 0-7: wave nw computes logit nw (2 FMA + butterfly)
        if (tid < 512) {
            float2 h2 = ((const float2*)hb4[cur ^ 1])[e];
            float pa = fw0 * h2.x + fw1 * h2.y;
            pa += dppf<QP_XOR1>(pa);
            pa += dppf<QP_XOR2>(pa);
            pa += swzf<SWZ_XOR4>(pa);
            pa += dppf<ROW_ROR8>(pa);
            pa += swzf<SWZ_XOR16>(pa);
            float psum = pa + __int_as_float(__builtin_amdgcn_readlane(__float_as_int(pa), 32));
            if (e == 0) part[(((size_t)dir * T_ + tt) * B_ + b) * N_ + nw] = psum;
        }
        pv_c = pv_n;
        cur ^= 1;
    }
}

// ---------------------------------------------------------------------------
// K2: Viterbi — replicated-score all-DPP version VERBATIM (r15, passing).
// ---------------------------------------------------------------------------
__global__ __launch_bounds__(64) void viterbi_kernel(
    const float* __restrict__ part,   // [2][T][B][8]
    const float* __restrict__ fc_b,
    const float* __restrict__ start_t,
    const float* __restrict__ end_t,
    const float* __restrict__ trans,  // [8][8]
    int* __restrict__ out)            // [B][T]
{
    int b = blockIdx.x;
    int l = threadIdx.x;
    int j = (l & 3) | ((l >> 1) & 4);
    bool b0c = (l & 1) != 0;
    bool b1c = (l & 2) != 0;
    bool b3c = (l & 8) != 0;
    int sh3 = 3 * j;

    __shared__ unsigned int hist_l[T_];

    float tr[8];
#pragma unroll
    for (int i = 0; i < 8; ++i) tr[i] = trans[i * 8 + j];   // column j
    float endt_r[8];
#pragma unroll
    for (int i = 0; i < 8; ++i) endt_r[i] = end_t[i];
    float fcb = fc_b[j];
    const float* pf = part;
    const float* pb = part + (size_t)T_ * B_ * N_;

    float s[8];

#define SHARE(xx) { \
    float y_ = dppf<QP_XOR1>(xx); \
    float A0 = b0c ? y_ : (xx); float A1 = b0c ? (xx) : y_; \
    float A0x = dppf<QP_XOR2>(A0); float A1x = dppf<QP_XOR2>(A1); \
    float B00 = b1c ? A0x : A0; float B10 = b1c ? A0 : A0x; \
    float B01 = b1c ? A1x : A1; float B11 = b1c ? A1 : A1x; \
    float C00 = dppf<ROW_ROR8>(B00); float C01 = dppf<ROW_ROR8>(B01); \
    float C10 = dppf<ROW_ROR8>(B10); float C11 = dppf<ROW_ROR8>(B11); \
    s[0] = b3c ? C00 : B00;  s[1] = b3c ? C01 : B01; \
    s[2] = b3c ? C10 : B10;  s[3] = b3c ? C11 : B11; \
    s[4] = b3c ? B00 : C00;  s[5] = b3c ? B01 : C01; \
    s[6] = b3c ? B10 : C10;  s[7] = b3c ? B11 : C11; }

#define VSTEP(emv, tcur) { \
    float v0 = (s[0] + tr[0]) + (emv); \
    float v1 = (s[1] + tr[1]) + (emv); \
    float v2 = (s[2] + tr[2]) + (emv); \
    float v3 = (s[3] + tr[3]) + (emv); \
    float v4 = (s[4] + tr[4]) + (emv); \
    float v5 = (s[5] + tr[5]) + (emv); \
    float v6 = (s[6] + tr[6]) + (emv); \
    float v7 = (s[7] + tr[7]) + (emv); \
    float va = (v1 > v0) ? v1 : v0;  int ia = (v1 > v0) ? 1 : 0; \
    float vb = (v3 > v2) ? v3 : v2;  int ib = (v3 > v2) ? 3 : 2; \
    float vc = (v5 > v4) ? v5 : v4;  int ic = (v5 > v4) ? 5 : 4; \
    float vd = (v7 > v6) ? v7 : v6;  int id_ = (v7 > v6) ? 7 : 6; \
    float ve = (vb > va) ? vb : va;  int ie = (vb > va) ? ib : ia; \
    float vf = (vd > vc) ? vd : vc;  int if_ = (vd > vc) ? id_ : ic; \
    float vg = (vf > ve) ? vf : ve;  int ig = (vf > ve) ? if_ : ie; \
    SHARE(vg) \
    unsigned pk = (unsigned)ig << sh3; \
    pk |= (unsigned)dppi<QP_XOR1>((int)pk); \
    pk |= (unsigned)dppi<QP_XOR2>((int)pk); \
    pk |= (unsigned)dppi<ROW_ROR8>((int)pk); \
    if (l == 0) hist_l[tcur] = pk; }

#define LOADSUB(dst, ss) { \
    int t0_ = (ss) * 8; \
    _Pragma("unroll") \
    for (int p = 0; p < 8; ++p) { \
        size_t base = ((size_t)(t0_ + p) * B_ + b) * N_ + j; \
        dst[p] = (pf[base] + pb[base]) + fcb; } }

#define PROC8(arr, t0_) { \
    VSTEP(arr[0], (t0_) + 0) VSTEP(arr[1], (t0_) + 1) \
    VSTEP(arr[2], (t0_) + 2) VSTEP(arr[3], (t0_) + 3) \
    VSTEP(arr[4], (t0_) + 4) VSTEP(arr[5], (t0_) + 5) \
    VSTEP(arr[6], (t0_) + 6) VSTEP(arr[7], (t0_) + 7) }

    float emA[8], emB[8];
    LOADSUB(emA, 0)
    LOADSUB(emB, 1)

    {
        float x0 = start_t[j] + emA[0];
        SHARE(x0)
    }
    VSTEP(emA[1], 1) VSTEP(emA[2], 2) VSTEP(emA[3], 3) VSTEP(emA[4], 4)
    VSTEP(emA[5], 5) VSTEP(emA[6], 6) VSTEP(emA[7], 7)

    for (int ss = 1; ss < 127; ss += 2) {
        LOADSUB(emA, ss + 1)
        PROC8(emB, ss * 8)
        LOADSUB(emB, ss + 2)
        PROC8(emA, (ss + 1) * 8)
    }
    PROC8(emB, 127 * 8)

    int tag;
    {
        float v0 = s[0] + endt_r[0];
        float v1 = s[1] + endt_r[1];
        float v2 = s[2] + endt_r[2];
        float v3 = s[3] + endt_r[3];
        float v4 = s[4] + endt_r[4];
        float v5 = s[5] + endt_r[5];
        float v6 = s[6] + endt_r[6];
        float v7 = s[7] + endt_r[7];
        float va = (v1 > v0) ? v1 : v0;  int ia = (v1 > v0) ? 1 : 0;
        float vb = (v3 > v2) ? v3 : v2;  int ib = (v3 > v2) ? 3 : 2;
        float vc = (v5 > v4) ? v5 : v4;  int ic = (v5 > v4) ? 5 : 4;
        float vd = (v7 > v6) ? v7 : v6;  int id_ = (v7 > v6) ? 7 : 6;
        float ve = (vb > va) ? vb : va;  int ie = (vb > va) ? ib : ia;
        float vf = (vd > vc) ? vd : vc;  int if_ = (vd > vc) ? id_ : ic;
        tag = (vf > ve) ? if_ : ie;
    }
    if (l == 0) out[(size_t)b * T_ + (T_ - 1)] = tag;
    __syncthreads();

    for (int t0b = T_ - 16; t0b >= 0; t0b -= 16) {
        unsigned int pk[16];
#pragma unroll
        for (int qq = 0; qq < 16; ++qq) pk[qq] = hist_l[t0b + qq];
#pragma unroll
        for (int qq = 15; qq >= 0; --qq) {
            int t = t0b + qq;
            if (t >= 1) {
                tag = (pk[qq] >> (3 * tag)) & 7;
                if (l == 0) out[(size_t)b * T_ + t - 1] = tag;
            }
        }
    }
#undef SHARE
#undef VSTEP
#undef LOADSUB
#undef PROC8
}

extern "C" void kernel_launch(void* const* d_in, const int* in_sizes, int n_in,
                              void* d_out, int out_size, void* d_ws, size_t ws_size,
                              hipStream_t stream) {
    (void)in_sizes; (void)n_in; (void)out_size; (void)ws_size;
    const int*   x      = (const int*)  d_in[0];
    const float* emb    = (const float*)d_in[1];
    const float* Wih_f  = (const float*)d_in[2];
    const float* Whh_f  = (const float*)d_in[3];
    const float* b_f    = (const float*)d_in[4];
    const float* Wih_b  = (const float*)d_in[5];
    const float* Whh_b  = (const float*)d_in[6];
    const float* b_b    = (const float*)d_in[7];
    const float* fcW    = (const float*)d_in[8];
    const float* fcb    = (const float*)d_in[9];
    const float* startt = (const float*)d_in[10];
    const float* endt   = (const float*)d_in[11];
    const float* trans  = (const float*)d_in[12];

    float* proj = (float*)d_ws;                    // 2*32*512 floats = 128 KB
    float* part = proj + 2 * V_ * G_;              // 2*1024*64*8 floats = 4 MB
    int*   out  = (int*)d_out;

    proj_kernel<<<64, 512, 0, stream>>>(emb, Wih_f, b_f, Wih_b, b_b, proj);
    lstm_kernel<<<128, 1024, 0, stream>>>(x, Whh_f, Whh_b, proj, fcW, part);
    viterbi_kernel<<<64, 64, 0, stream>>>(part, fcb, startt, endt, trans, out);
}